// Round 3
// baseline (406.725 us; speedup 1.0000x reference)
//
#include <hip/hip_runtime.h>
#include <stdint.h>

// Problem constants (fixed by reference setup_inputs).
#define N_REF   500000
#define N_PC    128
#define N_FEAT  2000
#define TOPK    16

#define K1_BLOCKS  2048
#define K1_THREADS 256
#define K1_WAVES   (K1_BLOCKS * (K1_THREADS / 64))   // 8192 waves (exactly resident)
#define N_QUAD     (N_REF / 4)                        // 125000 row-quads

#define PROJ_BLOCKS 16                                // 2000 = 16 * 125
#define FEAT_PER_BLK 125

#define K2_BLOCKS  128
#define NCAND      (K2_BLOCKS * TOPK)                 // 2048 candidates

typedef unsigned long long u64;

// ---------------------------------------------------------------------------
// Branchless insert of x into ascending sorted top[0..15] (drops the max).
__device__ __forceinline__ void insert16(u64* top, u64 x) {
#pragma unroll
    for (int i = 15; i >= 1; --i) {
        u64 lo = top[i - 1];
        u64 hi = (x > lo) ? x : lo;            // max(old top[i-1], x)
        top[i] = (top[i] < hi) ? top[i] : hi;  // min(old top[i], hi)
    }
    top[0] = (top[0] < x) ? top[0] : x;
}

// Bitonic sort of 64 values across the 64 lanes of a wave (ascending).
__device__ __forceinline__ u64 bitonic_sort64(u64 v, int lane) {
#pragma unroll
    for (int k = 2; k <= 64; k <<= 1) {
#pragma unroll
        for (int j = k >> 1; j >= 1; j >>= 1) {
            u64 o = __shfl_xor(v, j);
            bool up    = ((lane & k) == 0);
            bool lower = ((lane & j) == 0);
            u64 mn = (v < o) ? v : o;
            u64 mx = (v < o) ? o : v;
            v = (up == lower) ? mn : mx;
        }
    }
    return v;
}

// Per-wave merge of 64 ascending per-lane top-16 lists -> wave top-16 via
// 16-round min-pop (keys unique: row index lives in the low 32 bits).
__device__ __forceinline__ u64 wave_minpop16(u64* top, int lane) {
    u64 chosen = 0;
#pragma unroll
    for (int r = 0; r < TOPK; ++r) {
        u64 m = top[0];
#pragma unroll
        for (int off = 32; off >= 1; off >>= 1) {
            u64 o = __shfl_xor(m, off);
            m = (o < m) ? o : m;
        }
        if (top[0] == m) {          // exactly one lane pops
#pragma unroll
            for (int i = 0; i < TOPK - 1; ++i) top[i] = top[i + 1];
            top[TOPK - 1] = ~0ull;
        }
        if (lane == r) chosen = m;
    }
    return chosen;
}

// ---------------------------------------------------------------------------
// k0: partial projection. 16 blocks x 128 threads; block b handles features
// [125b, 125(b+1)). Also zeroes the last-block-done counter for k2.
__global__ void proj_partial(const float* __restrict__ din,
                             const float* __restrict__ T,
                             float* __restrict__ part,
                             unsigned* __restrict__ counter) {
    if (blockIdx.x == 0 && threadIdx.x == 0) *counter = 0u;
    int b = blockIdx.x;    // 0..15
    int t = threadIdx.x;   // 0..127
    int f0 = b * FEAT_PER_BLK;
    float acc = 0.f;
#pragma unroll 5
    for (int i = 0; i < FEAT_PER_BLK; ++i) {
        int f = f0 + i;
        acc += din[f] * T[(size_t)f * N_PC + t];
    }
    part[b * N_PC + t] = acc;
}

// ---------------------------------------------------------------------------
// k1: pure distance stream, unrolled x2: one wave handles 8 rows (2 quads,
// 4 KB) per iteration via 4 independent float4 loads + 4 interleaved
// butterfly chains. Branch-free body -> compiler pipelines loads. 8 waves/EU.
__global__ __launch_bounds__(K1_THREADS, 8) void dist_stream(
        const float* __restrict__ part,
        const float* __restrict__ ref,
        float* __restrict__ dist) {
    __shared__ __align__(16) float pc[N_PC];

    int tid  = threadIdx.x;
    int lane = tid & 63;
    int w    = tid >> 6;   // wave in block, 0..3

    if (tid < N_PC) {
        float s = 0.f;
#pragma unroll
        for (int b = 0; b < PROJ_BLOCKS; ++b) s += part[b * N_PC + tid];
        pc[tid] = s;
    }
    __syncthreads();

    // Each lane's 4 query components (fixed for the whole loop).
    float4 qv = reinterpret_cast<const float4*>(pc)[lane & 31];

    int gw = blockIdx.x * (K1_THREADS / 64) + w;
    const float4* ref4 = reinterpret_cast<const float4*>(ref);

    int g = gw;
    for (; g + K1_WAVES < N_QUAD; g += 2 * K1_WAVES) {
        int g2 = g + K1_WAVES;
        size_t b0 = (size_t)g  * 128;
        size_t b1 = (size_t)g2 * 128;
        float4 va = ref4[b0 + lane];
        float4 vb = ref4[b0 + 64 + lane];
        float4 vc = ref4[b1 + lane];
        float4 vd = ref4[b1 + 64 + lane];
        float d0 = fabsf(qv.x - va.x) + fabsf(qv.y - va.y)
                 + fabsf(qv.z - va.z) + fabsf(qv.w - va.w);
        float d1 = fabsf(qv.x - vb.x) + fabsf(qv.y - vb.y)
                 + fabsf(qv.z - vb.z) + fabsf(qv.w - vb.w);
        float d2 = fabsf(qv.x - vc.x) + fabsf(qv.y - vc.y)
                 + fabsf(qv.z - vc.z) + fabsf(qv.w - vc.w);
        float d3 = fabsf(qv.x - vd.x) + fabsf(qv.y - vd.y)
                 + fabsf(qv.z - vd.z) + fabsf(qv.w - vd.w);
#pragma unroll
        for (int off = 16; off >= 1; off >>= 1) {
            d0 += __shfl_xor(d0, off);
            d1 += __shfl_xor(d1, off);
            d2 += __shfl_xor(d2, off);
            d3 += __shfl_xor(d3, off);
        }
        if ((lane & 31) == 0) {
            int half = lane >> 5;                 // 0 or 1
            dist[4 * g  + half]     = d0;
            dist[4 * g  + 2 + half] = d1;
            dist[4 * g2 + half]     = d2;
            dist[4 * g2 + 2 + half] = d3;
        }
    }
    for (; g < N_QUAD; g += K1_WAVES) {
        size_t base = (size_t)g * 128;
        float4 va = ref4[base + lane];
        float4 vb = ref4[base + 64 + lane];
        float d0 = fabsf(qv.x - va.x) + fabsf(qv.y - va.y)
                 + fabsf(qv.z - va.z) + fabsf(qv.w - va.w);
        float d1 = fabsf(qv.x - vb.x) + fabsf(qv.y - vb.y)
                 + fabsf(qv.z - vb.z) + fabsf(qv.w - vb.w);
#pragma unroll
        for (int off = 16; off >= 1; off >>= 1) {
            d0 += __shfl_xor(d0, off);
            d1 += __shfl_xor(d1, off);
        }
        if ((lane & 31) == 0) {
            int half = lane >> 5;
            dist[4 * g + half]     = d0;
            dist[4 * g + 2 + half] = d1;
        }
    }
}

// ---------------------------------------------------------------------------
// k2: top-16 over dist[N_REF] (2 MB, LLC-resident) fused with the final merge
// via last-block-done. Per-lane insert16 on packed keys (dist>=0 so float
// bits preserve order), wave min-pop, block bitonic, then the last block
// merges all 2048 candidates, gathers psuedo, writes the mean.
__global__ __launch_bounds__(256) void topk_fused(
        const float* __restrict__ dist,
        const float* __restrict__ psuedo,
        u64* __restrict__ cand,
        unsigned* __restrict__ counter,
        float* __restrict__ out) {
    __shared__ u64 wl[64];
    __shared__ unsigned s_ticket;
    int tid  = threadIdx.x;
    int lane = tid & 63;
    int w    = tid >> 6;

    u64 top[TOPK];
#pragma unroll
    for (int i = 0; i < TOPK; ++i) top[i] = ~0ull;

    const float4* dist4 = reinterpret_cast<const float4*>(dist);
    for (int i = blockIdx.x * 256 + tid; i < N_REF / 4; i += K2_BLOCKS * 256) {
        float4 v = dist4[i];
        unsigned base = 4u * (unsigned)i;
        u64 k0 = (((u64)(unsigned)__float_as_int(v.x)) << 32) | (base + 0u);
        u64 k1 = (((u64)(unsigned)__float_as_int(v.y)) << 32) | (base + 1u);
        u64 k2 = (((u64)(unsigned)__float_as_int(v.z)) << 32) | (base + 2u);
        u64 k3 = (((u64)(unsigned)__float_as_int(v.w)) << 32) | (base + 3u);
        if (k0 < top[TOPK - 1]) insert16(top, k0);
        if (k1 < top[TOPK - 1]) insert16(top, k1);
        if (k2 < top[TOPK - 1]) insert16(top, k2);
        if (k3 < top[TOPK - 1]) insert16(top, k3);
    }

    u64 chosen = wave_minpop16(top, lane);
    if (lane < TOPK) wl[w * TOPK + lane] = chosen;
    __syncthreads();

    if (tid < 64) {
        u64 v = bitonic_sort64(wl[tid], tid);
        if (tid < TOPK) cand[blockIdx.x * TOPK + tid] = v;
    }

    // ---- last-block-done handoff ----
    __threadfence();                       // make cand writes device-visible
    __syncthreads();
    if (tid == 0) s_ticket = atomicAdd(counter, 1u);
    __syncthreads();
    if (s_ticket != K2_BLOCKS - 1) return;

    // Last block: merge NCAND candidates -> global top-16 -> mean.
    __threadfence();                       // order after observing all tickets
#pragma unroll
    for (int i = 0; i < TOPK; ++i) top[i] = ~0ull;
#pragma unroll
    for (int r = 0; r < NCAND / 256; ++r) {        // 8 per thread
        u64 x = cand[r * 256 + tid];
        if (x < top[TOPK - 1]) insert16(top, x);
    }
    chosen = wave_minpop16(top, lane);
    __syncthreads();                       // wl reuse
    if (lane < TOPK) wl[w * TOPK + lane] = chosen;
    __syncthreads();

    if (tid < 64) {
        u64 v = bitonic_sort64(wl[tid], tid);
        float p = 0.f;
        if (tid < TOPK) p = psuedo[(unsigned)(v & 0xffffffffull)];
#pragma unroll
        for (int off = 32; off >= 1; off >>= 1)
            p += __shfl_xor(p, off);
        if (tid == 0) out[0] = p * (1.0f / (float)TOPK);
    }
}

// ---------------------------------------------------------------------------
extern "C" void kernel_launch(void* const* d_in, const int* in_sizes, int n_in,
                              void* d_out, int out_size, void* d_ws, size_t ws_size,
                              hipStream_t stream) {
    const float* din = (const float*)d_in[0];   // [1, 2000]
    const float* T   = (const float*)d_in[1];   // [2000, 128]
    const float* ref = (const float*)d_in[2];   // [500000, 128]
    const float* ps  = (const float*)d_in[3];   // [500000]
    // d_in[4] is K == 16, baked in as TOPK.

    char* ws = (char*)d_ws;
    float*    part    = (float*)ws;                               // 16*128*4 = 8 KB
    float*    dist    = (float*)(ws + 32768);                     // 500000*4 = 2 MB
    u64*      cand    = (u64*)(ws + 32768 + N_REF * 4);           // 2048*8 = 16 KB
    unsigned* counter = (unsigned*)(ws + 32768 + N_REF * 4 + NCAND * 8);
    float*    outp    = (float*)d_out;

    proj_partial<<<PROJ_BLOCKS, 128, 0, stream>>>(din, T, part, counter);
    dist_stream<<<K1_BLOCKS, K1_THREADS, 0, stream>>>(part, ref, dist);
    topk_fused<<<K2_BLOCKS, 256, 0, stream>>>(dist, ps, cand, counter, outp);
}

// Round 4
// 396.766 us; speedup vs baseline: 1.0251x; 1.0251x over previous
//
#include <hip/hip_runtime.h>
#include <stdint.h>

// Problem constants (fixed by reference setup_inputs).
#define N_REF   500000
#define N_PC    128
#define N_FEAT  2000
#define TOPK    16

#define K1_BLOCKS  2048
#define K1_THREADS 256
#define K1_WAVES   (K1_BLOCKS * (K1_THREADS / 64))   // 8192 waves (exactly resident)
#define N_QUAD     (N_REF / 4)                        // 125000 row-quads

#define PROJ_BLOCKS 16                                // 2000 = 16 * 125
#define FEAT_PER_BLK 125

#define K2_BLOCKS  128
#define NCAND      (K2_BLOCKS * TOPK)                 // 2048 candidates

typedef unsigned long long u64;

// ---------------------------------------------------------------------------
// Branchless insert of x into ascending sorted top[0..15] (drops the max).
__device__ __forceinline__ void insert16(u64* top, u64 x) {
#pragma unroll
    for (int i = 15; i >= 1; --i) {
        u64 lo = top[i - 1];
        u64 hi = (x > lo) ? x : lo;            // max(old top[i-1], x)
        top[i] = (top[i] < hi) ? top[i] : hi;  // min(old top[i], hi)
    }
    top[0] = (top[0] < x) ? top[0] : x;
}

// Bitonic sort of 64 values across the 64 lanes of a wave (ascending).
__device__ __forceinline__ u64 bitonic_sort64(u64 v, int lane) {
#pragma unroll
    for (int k = 2; k <= 64; k <<= 1) {
#pragma unroll
        for (int j = k >> 1; j >= 1; j >>= 1) {
            u64 o = __shfl_xor(v, j);
            bool up    = ((lane & k) == 0);
            bool lower = ((lane & j) == 0);
            u64 mn = (v < o) ? v : o;
            u64 mx = (v < o) ? o : v;
            v = (up == lower) ? mn : mx;
        }
    }
    return v;
}

// Per-wave merge of 64 ascending per-lane top-16 lists -> wave top-16 via
// 16-round min-pop (keys unique: row index lives in the low 32 bits).
__device__ __forceinline__ u64 wave_minpop16(u64* top, int lane) {
    u64 chosen = 0;
#pragma unroll
    for (int r = 0; r < TOPK; ++r) {
        u64 m = top[0];
#pragma unroll
        for (int off = 32; off >= 1; off >>= 1) {
            u64 o = __shfl_xor(m, off);
            m = (o < m) ? o : m;
        }
        if (top[0] == m) {          // exactly one lane pops
#pragma unroll
            for (int i = 0; i < TOPK - 1; ++i) top[i] = top[i + 1];
            top[TOPK - 1] = ~0ull;
        }
        if (lane == r) chosen = m;
    }
    return chosen;
}

// ---------------------------------------------------------------------------
// k0: partial projection. 16 blocks x 128 threads; block b handles features
// [125b, 125(b+1)). Also zeroes the last-block-done counter for k2.
__global__ void proj_partial(const float* __restrict__ din,
                             const float* __restrict__ T,
                             float* __restrict__ part,
                             unsigned* __restrict__ counter) {
    if (blockIdx.x == 0 && threadIdx.x == 0) *counter = 0u;
    int b = blockIdx.x;    // 0..15
    int t = threadIdx.x;   // 0..127
    int f0 = b * FEAT_PER_BLK;
    float acc = 0.f;
#pragma unroll 5
    for (int i = 0; i < FEAT_PER_BLK; ++i) {
        int f = f0 + i;
        acc += din[f] * T[(size_t)f * N_PC + t];
    }
    part[b * N_PC + t] = acc;
}

// ---------------------------------------------------------------------------
// k1: pure distance stream (R1 form — the verified-fast body). One wave does
// 4 rows (1 quad, 2 KB) per iteration via two independent float4 loads + two
// interleaved butterfly chains. Branch-free; 32 resident waves/CU give
// 64 KB/CU in flight >> 9 KB latency-BW product, so this is BW-bound.
// NOTE: do NOT add a min-waves launch bound or x2 unroll — R2 showed the
// 64-VGPR cap + 4 in-flight loads serializes the stream (+12 us).
__global__ __launch_bounds__(K1_THREADS) void dist_stream(
        const float* __restrict__ part,
        const float* __restrict__ ref,
        float* __restrict__ dist) {
    __shared__ __align__(16) float pc[N_PC];

    int tid  = threadIdx.x;
    int lane = tid & 63;
    int w    = tid >> 6;   // wave in block, 0..3

    if (tid < N_PC) {
        float s = 0.f;
#pragma unroll
        for (int b = 0; b < PROJ_BLOCKS; ++b) s += part[b * N_PC + tid];
        pc[tid] = s;
    }
    __syncthreads();

    // Each lane's 4 query components (fixed for the whole loop).
    float4 qv = reinterpret_cast<const float4*>(pc)[lane & 31];

    int gw = blockIdx.x * (K1_THREADS / 64) + w;
    const float4* ref4 = reinterpret_cast<const float4*>(ref);

    for (int g = gw; g < N_QUAD; g += K1_WAVES) {
        size_t base = (size_t)g * 128;            // 4 rows = 128 float4
        float4 va = ref4[base + lane];            // rows 4g, 4g+1
        float4 vb = ref4[base + 64 + lane];       // rows 4g+2, 4g+3
        float d0 = fabsf(qv.x - va.x) + fabsf(qv.y - va.y)
                 + fabsf(qv.z - va.z) + fabsf(qv.w - va.w);
        float d1 = fabsf(qv.x - vb.x) + fabsf(qv.y - vb.y)
                 + fabsf(qv.z - vb.z) + fabsf(qv.w - vb.w);
        // xor offsets <=16 stay within each 32-lane half: lanes 0..31 end
        // with row (4g+0 / 4g+2) sums, lanes 32..63 with (4g+1 / 4g+3).
#pragma unroll
        for (int off = 16; off >= 1; off >>= 1) {
            d0 += __shfl_xor(d0, off);
            d1 += __shfl_xor(d1, off);
        }
        if ((lane & 31) == 0) {
            int half = lane >> 5;                 // 0 or 1
            dist[4 * g + half]     = d0;
            dist[4 * g + 2 + half] = d1;
        }
    }
}

// ---------------------------------------------------------------------------
// k2: top-16 over dist[N_REF] (2 MB, LLC-resident) fused with the final merge
// via last-block-done. Per-lane insert16 on packed keys (dist>=0 so float
// bits preserve order), wave min-pop, block bitonic, then the last block
// merges all 2048 candidates, gathers psuedo, writes the mean.
__global__ __launch_bounds__(256) void topk_fused(
        const float* __restrict__ dist,
        const float* __restrict__ psuedo,
        u64* __restrict__ cand,
        unsigned* __restrict__ counter,
        float* __restrict__ out) {
    __shared__ u64 wl[64];
    __shared__ unsigned s_ticket;
    int tid  = threadIdx.x;
    int lane = tid & 63;
    int w    = tid >> 6;

    u64 top[TOPK];
#pragma unroll
    for (int i = 0; i < TOPK; ++i) top[i] = ~0ull;

    const float4* dist4 = reinterpret_cast<const float4*>(dist);
    for (int i = blockIdx.x * 256 + tid; i < N_REF / 4; i += K2_BLOCKS * 256) {
        float4 v = dist4[i];
        unsigned base = 4u * (unsigned)i;
        u64 k0 = (((u64)(unsigned)__float_as_int(v.x)) << 32) | (base + 0u);
        u64 k1 = (((u64)(unsigned)__float_as_int(v.y)) << 32) | (base + 1u);
        u64 k2 = (((u64)(unsigned)__float_as_int(v.z)) << 32) | (base + 2u);
        u64 k3 = (((u64)(unsigned)__float_as_int(v.w)) << 32) | (base + 3u);
        if (k0 < top[TOPK - 1]) insert16(top, k0);
        if (k1 < top[TOPK - 1]) insert16(top, k1);
        if (k2 < top[TOPK - 1]) insert16(top, k2);
        if (k3 < top[TOPK - 1]) insert16(top, k3);
    }

    u64 chosen = wave_minpop16(top, lane);
    if (lane < TOPK) wl[w * TOPK + lane] = chosen;
    __syncthreads();

    if (tid < 64) {
        u64 v = bitonic_sort64(wl[tid], tid);
        if (tid < TOPK) cand[blockIdx.x * TOPK + tid] = v;
    }

    // ---- last-block-done handoff ----
    __threadfence();                       // make cand writes device-visible
    __syncthreads();
    if (tid == 0) s_ticket = atomicAdd(counter, 1u);
    __syncthreads();
    if (s_ticket != K2_BLOCKS - 1) return;

    // Last block: merge NCAND candidates -> global top-16 -> mean.
    __threadfence();                       // order after observing all tickets
#pragma unroll
    for (int i = 0; i < TOPK; ++i) top[i] = ~0ull;
#pragma unroll
    for (int r = 0; r < NCAND / 256; ++r) {        // 8 per thread
        u64 x = cand[r * 256 + tid];
        if (x < top[TOPK - 1]) insert16(top, x);
    }
    chosen = wave_minpop16(top, lane);
    __syncthreads();                       // wl reuse
    if (lane < TOPK) wl[w * TOPK + lane] = chosen;
    __syncthreads();

    if (tid < 64) {
        u64 v = bitonic_sort64(wl[tid], tid);
        float p = 0.f;
        if (tid < TOPK) p = psuedo[(unsigned)(v & 0xffffffffull)];
#pragma unroll
        for (int off = 32; off >= 1; off >>= 1)
            p += __shfl_xor(p, off);
        if (tid == 0) out[0] = p * (1.0f / (float)TOPK);
    }
}

// ---------------------------------------------------------------------------
extern "C" void kernel_launch(void* const* d_in, const int* in_sizes, int n_in,
                              void* d_out, int out_size, void* d_ws, size_t ws_size,
                              hipStream_t stream) {
    const float* din = (const float*)d_in[0];   // [1, 2000]
    const float* T   = (const float*)d_in[1];   // [2000, 128]
    const float* ref = (const float*)d_in[2];   // [500000, 128]
    const float* ps  = (const float*)d_in[3];   // [500000]
    // d_in[4] is K == 16, baked in as TOPK.

    char* ws = (char*)d_ws;
    float*    part    = (float*)ws;                               // 16*128*4 = 8 KB
    float*    dist    = (float*)(ws + 32768);                     // 500000*4 = 2 MB
    u64*      cand    = (u64*)(ws + 32768 + N_REF * 4);           // 2048*8 = 16 KB
    unsigned* counter = (unsigned*)(ws + 32768 + N_REF * 4 + NCAND * 8);
    float*    outp    = (float*)d_out;

    proj_partial<<<PROJ_BLOCKS, 128, 0, stream>>>(din, T, part, counter);
    dist_stream<<<K1_BLOCKS, K1_THREADS, 0, stream>>>(part, ref, dist);
    topk_fused<<<K2_BLOCKS, 256, 0, stream>>>(dist, ps, cand, counter, outp);
}

// Round 5
// 394.932 us; speedup vs baseline: 1.0299x; 1.0046x over previous
//
#include <hip/hip_runtime.h>
#include <stdint.h>

// Problem constants (fixed by reference setup_inputs).
#define N_REF   500000
#define N_PC    128
#define N_FEAT  2000
#define TOPK    16

#define K1_BLOCKS  2048
#define K1_THREADS 256
#define K1_WAVES   (K1_BLOCKS * (K1_THREADS / 64))   // 8192 waves
#define N_QUAD     (N_REF / 4)                        // 125000 row-quads

#define PROJ_BLOCKS 40                                // 2000 = 40 * 50
#define FEAT_PER_BLK 50

#define K2_BLOCKS  128
#define NCAND      (K2_BLOCKS * TOPK)                 // 2048 candidates

typedef unsigned long long u64;

// ---------------------------------------------------------------------------
// Branchless insert of x into ascending sorted top[0..15] (drops the max).
__device__ __forceinline__ void insert16(u64* top, u64 x) {
#pragma unroll
    for (int i = 15; i >= 1; --i) {
        u64 lo = top[i - 1];
        u64 hi = (x > lo) ? x : lo;            // max(old top[i-1], x)
        top[i] = (top[i] < hi) ? top[i] : hi;  // min(old top[i], hi)
    }
    top[0] = (top[0] < x) ? top[0] : x;
}

// Bitonic sort of 64 values across the 64 lanes of a wave (ascending).
__device__ __forceinline__ u64 bitonic_sort64(u64 v, int lane) {
#pragma unroll
    for (int k = 2; k <= 64; k <<= 1) {
#pragma unroll
        for (int j = k >> 1; j >= 1; j >>= 1) {
            u64 o = __shfl_xor(v, j);
            bool up    = ((lane & k) == 0);
            bool lower = ((lane & j) == 0);
            u64 mn = (v < o) ? v : o;
            u64 mx = (v < o) ? o : v;
            v = (up == lower) ? mn : mx;
        }
    }
    return v;
}

// Per-wave merge of 64 ascending per-lane top-16 lists -> wave top-16 via
// 16-round min-pop (keys unique: row index lives in the low 32 bits).
__device__ __forceinline__ u64 wave_minpop16(u64* top, int lane) {
    u64 chosen = 0;
#pragma unroll
    for (int r = 0; r < TOPK; ++r) {
        u64 m = top[0];
#pragma unroll
        for (int off = 32; off >= 1; off >>= 1) {
            u64 o = __shfl_xor(m, off);
            m = (o < m) ? o : m;
        }
        if (top[0] == m) {          // exactly one lane pops
#pragma unroll
            for (int i = 0; i < TOPK - 1; ++i) top[i] = top[i + 1];
            top[TOPK - 1] = ~0ull;
        }
        if (lane == r) chosen = m;
    }
    return chosen;
}

// ---------------------------------------------------------------------------
// k0: partial projection. 40 blocks x 128 threads; block b handles features
// [50b, 50(b+1)). 40 blocks (not 16): cold-HBM latency on the 1 MB T read is
// the cost driver here — R1(40)=394.1 vs R4(16)=396.8 us total.
// Also zeroes the last-block-done counter for k2.
__global__ void proj_partial(const float* __restrict__ din,
                             const float* __restrict__ T,
                             float* __restrict__ part,
                             unsigned* __restrict__ counter) {
    if (blockIdx.x == 0 && threadIdx.x == 0) *counter = 0u;
    int b = blockIdx.x;    // 0..39
    int t = threadIdx.x;   // 0..127
    int f0 = b * FEAT_PER_BLK;
    float acc = 0.f;
#pragma unroll 10
    for (int i = 0; i < FEAT_PER_BLK; ++i) {
        int f = f0 + i;
        acc += din[f] * T[(size_t)f * N_PC + t];
    }
    part[b * N_PC + t] = acc;
}

// ---------------------------------------------------------------------------
// k1: pure distance stream (R1 form — the verified-fast body). One wave does
// 4 rows (1 quad, 2 KB) per iteration via two independent float4 loads + two
// interleaved butterfly chains. Branch-free; 32 resident waves/CU give
// 64 KB/CU in flight >> 9 KB latency-BW product, so this is BW-bound.
// NOTE: do NOT add a min-waves launch bound or x2 unroll — R2 showed the
// 64-VGPR cap + 4 in-flight loads serializes the stream (+12 us).
__global__ __launch_bounds__(K1_THREADS) void dist_stream(
        const float* __restrict__ part,
        const float* __restrict__ ref,
        float* __restrict__ dist) {
    __shared__ __align__(16) float pc[N_PC];

    int tid  = threadIdx.x;
    int lane = tid & 63;
    int w    = tid >> 6;   // wave in block, 0..3

    if (tid < N_PC) {
        float s = 0.f;
#pragma unroll
        for (int b = 0; b < PROJ_BLOCKS; ++b) s += part[b * N_PC + tid];
        pc[tid] = s;
    }
    __syncthreads();

    // Each lane's 4 query components (fixed for the whole loop).
    float4 qv = reinterpret_cast<const float4*>(pc)[lane & 31];

    int gw = blockIdx.x * (K1_THREADS / 64) + w;
    const float4* ref4 = reinterpret_cast<const float4*>(ref);

    for (int g = gw; g < N_QUAD; g += K1_WAVES) {
        size_t base = (size_t)g * 128;            // 4 rows = 128 float4
        float4 va = ref4[base + lane];            // rows 4g, 4g+1
        float4 vb = ref4[base + 64 + lane];       // rows 4g+2, 4g+3
        float d0 = fabsf(qv.x - va.x) + fabsf(qv.y - va.y)
                 + fabsf(qv.z - va.z) + fabsf(qv.w - va.w);
        float d1 = fabsf(qv.x - vb.x) + fabsf(qv.y - vb.y)
                 + fabsf(qv.z - vb.z) + fabsf(qv.w - vb.w);
        // xor offsets <=16 stay within each 32-lane half: lanes 0..31 end
        // with row (4g+0 / 4g+2) sums, lanes 32..63 with (4g+1 / 4g+3).
#pragma unroll
        for (int off = 16; off >= 1; off >>= 1) {
            d0 += __shfl_xor(d0, off);
            d1 += __shfl_xor(d1, off);
        }
        if ((lane & 31) == 0) {
            int half = lane >> 5;                 // 0 or 1
            dist[4 * g + half]     = d0;
            dist[4 * g + 2 + half] = d1;
        }
    }
}

// ---------------------------------------------------------------------------
// k2: top-16 over dist[N_REF] (2 MB, LLC-resident) fused with the final merge
// via last-block-done. Per-lane insert16 on packed keys (dist>=0 so float
// bits preserve order), wave min-pop, block bitonic, then the last block
// merges all 2048 candidates, gathers psuedo, writes the mean.
__global__ __launch_bounds__(256) void topk_fused(
        const float* __restrict__ dist,
        const float* __restrict__ psuedo,
        u64* __restrict__ cand,
        unsigned* __restrict__ counter,
        float* __restrict__ out) {
    __shared__ u64 wl[64];
    __shared__ unsigned s_ticket;
    int tid  = threadIdx.x;
    int lane = tid & 63;
    int w    = tid >> 6;

    u64 top[TOPK];
#pragma unroll
    for (int i = 0; i < TOPK; ++i) top[i] = ~0ull;

    const float4* dist4 = reinterpret_cast<const float4*>(dist);
    for (int i = blockIdx.x * 256 + tid; i < N_REF / 4; i += K2_BLOCKS * 256) {
        float4 v = dist4[i];
        unsigned base = 4u * (unsigned)i;
        u64 k0 = (((u64)(unsigned)__float_as_int(v.x)) << 32) | (base + 0u);
        u64 k1 = (((u64)(unsigned)__float_as_int(v.y)) << 32) | (base + 1u);
        u64 k2 = (((u64)(unsigned)__float_as_int(v.z)) << 32) | (base + 2u);
        u64 k3 = (((u64)(unsigned)__float_as_int(v.w)) << 32) | (base + 3u);
        if (k0 < top[TOPK - 1]) insert16(top, k0);
        if (k1 < top[TOPK - 1]) insert16(top, k1);
        if (k2 < top[TOPK - 1]) insert16(top, k2);
        if (k3 < top[TOPK - 1]) insert16(top, k3);
    }

    u64 chosen = wave_minpop16(top, lane);
    if (lane < TOPK) wl[w * TOPK + lane] = chosen;
    __syncthreads();

    if (tid < 64) {
        u64 v = bitonic_sort64(wl[tid], tid);
        if (tid < TOPK) cand[blockIdx.x * TOPK + tid] = v;
    }

    // ---- last-block-done handoff ----
    __threadfence();                       // make cand writes device-visible
    __syncthreads();
    if (tid == 0) s_ticket = atomicAdd(counter, 1u);
    __syncthreads();
    if (s_ticket != K2_BLOCKS - 1) return;

    // Last block: merge NCAND candidates -> global top-16 -> mean.
    __threadfence();                       // order after observing all tickets
#pragma unroll
    for (int i = 0; i < TOPK; ++i) top[i] = ~0ull;
#pragma unroll
    for (int r = 0; r < NCAND / 256; ++r) {        // 8 per thread
        u64 x = cand[r * 256 + tid];
        if (x < top[TOPK - 1]) insert16(top, x);
    }
    chosen = wave_minpop16(top, lane);
    __syncthreads();                       // wl reuse
    if (lane < TOPK) wl[w * TOPK + lane] = chosen;
    __syncthreads();

    if (tid < 64) {
        u64 v = bitonic_sort64(wl[tid], tid);
        float p = 0.f;
        if (tid < TOPK) p = psuedo[(unsigned)(v & 0xffffffffull)];
#pragma unroll
        for (int off = 32; off >= 1; off >>= 1)
            p += __shfl_xor(p, off);
        if (tid == 0) out[0] = p * (1.0f / (float)TOPK);
    }
}

// ---------------------------------------------------------------------------
extern "C" void kernel_launch(void* const* d_in, const int* in_sizes, int n_in,
                              void* d_out, int out_size, void* d_ws, size_t ws_size,
                              hipStream_t stream) {
    const float* din = (const float*)d_in[0];   // [1, 2000]
    const float* T   = (const float*)d_in[1];   // [2000, 128]
    const float* ref = (const float*)d_in[2];   // [500000, 128]
    const float* ps  = (const float*)d_in[3];   // [500000]
    // d_in[4] is K == 16, baked in as TOPK.

    char* ws = (char*)d_ws;
    float*    part    = (float*)ws;                               // 40*128*4 = 20 KB
    float*    dist    = (float*)(ws + 32768);                     // 500000*4 = 2 MB
    u64*      cand    = (u64*)(ws + 32768 + N_REF * 4);           // 2048*8 = 16 KB
    unsigned* counter = (unsigned*)(ws + 32768 + N_REF * 4 + NCAND * 8);
    float*    outp    = (float*)d_out;

    proj_partial<<<PROJ_BLOCKS, 128, 0, stream>>>(din, T, part, counter);
    dist_stream<<<K1_BLOCKS, K1_THREADS, 0, stream>>>(part, ref, dist);
    topk_fused<<<K2_BLOCKS, 256, 0, stream>>>(dist, ps, cand, counter, outp);
}